// Round 15
// baseline (10618.325 us; speedup 1.0000x reference)
//
#include <hip/hip_runtime.h>
#include <hip/hip_bf16.h>
#include <math.h>

typedef __bf16 bf16_t;
typedef float  f32x4  __attribute__((ext_vector_type(4)));
typedef float  f32x16 __attribute__((ext_vector_type(16)));
typedef int    i32x4  __attribute__((ext_vector_type(4)));
typedef int    i32x8  __attribute__((ext_vector_type(8)));
typedef unsigned int uint32;
typedef unsigned char uint8;

// ---------------- workspace layout (bytes) ----------------
#define WS_WSP    0        // 1297 f32
#define WS_AH     5248     // 256 f32
#define WS_U527   6272     // 527 f32
#define WS_BIAS   8384     // 1 f32
#define WS_BIASG  8448     // 1024 f32
#define WS_WC     12544    // 327680 B fp8 weights: 10 units x 32KB

// Hardware-rate gate math: v_exp_f32 (exp2) + v_rcp_f32, ~1ulp, exact saturation.
__device__ __forceinline__ float sigmoid_hw(float x) {
    float e = __builtin_amdgcn_exp2f(-1.44269504f * x);
    return __builtin_amdgcn_rcpf(1.f + e);
}
__device__ __forceinline__ float tanh_hw(float x) {
    float e = __builtin_amdgcn_exp2f(2.88539008f * x);
    return 1.f - 2.f * __builtin_amdgcn_rcpf(1.f + e);
}

// ---------------- head/spatial weight composition (tiny) ----------------
__global__ void k_head(const float* __restrict__ sl_w, const float* __restrict__ sl_b,
                       const float* __restrict__ st_w, const float* __restrict__ st_b,
                       const float* __restrict__ seg_b,
                       const float* __restrict__ l1_w, const float* __restrict__ l1_b,
                       const float* __restrict__ l2_w, const float* __restrict__ l2_b,
                       const float* __restrict__ l4_w, const float* __restrict__ l4_b,
                       const float* __restrict__ l5_w, const float* __restrict__ l5_b,
                       const float* __restrict__ l6_w, const float* __restrict__ l6_b,
                       const float* __restrict__ l7_w, const float* __restrict__ l7_b,
                       float* __restrict__ wsp, float* __restrict__ ah,
                       float* __restrict__ u527_out, float* __restrict__ bias_out) {
    __shared__ float v2[128], v3[256], aa[384], u256[256], u527[527];
    __shared__ float red[8];
    const int t = threadIdx.x;   // 512 threads

    if (t < 128) { float s = 0.f; for (int i = 0; i < 128; ++i) s += l7_w[i] * l6_w[i*128 + t]; v2[t] = s; }
    __syncthreads();
    if (t < 256) { float s = 0.f; for (int i = 0; i < 128; ++i) s += v2[i] * l5_w[i*256 + t]; v3[t] = s; }
    __syncthreads();
    if (t < 384) { float s = 0.f; for (int i = 0; i < 256; ++i) s += v3[i] * l4_w[i*384 + t]; aa[t] = s; }
    __syncthreads();
    if (t < 256) { float s = 0.f; for (int i = 0; i < 128; ++i) s += aa[i] * l2_w[i*256 + t]; u256[t] = s; }
    if (t < 256) ah[t] = aa[128 + t];
    __syncthreads();
    for (int j = t; j < 527; j += 512) {
        float s = 0.f;
        for (int i = 0; i < 256; ++i) s += u256[i] * l1_w[i*527 + j];
        u527[j] = s; u527_out[j] = s;
    }
    __syncthreads();
    if (t < 4)              { float s = 0.f; for (int i = 0; i < 2; ++i) s += u527[i]     * sl_w[i*4  + t];      wsp[t] = s; }
    else if (t < 16)        { int c = t - 4;  float s = 0.f; for (int i = 0; i < 8; ++i) s += u527[2+i] * st_w[i*12 + c]; wsp[t] = s; }
    else if (t < 21)        { wsp[1292 + (t - 16)] = u527[522 + (t - 16)]; }
    float p = 0.f;
    if (t < 128) p += l7_w[t] * l6_b[t] + v2[t] * l5_b[t] + aa[t] * l2_b[t];
    if (t < 256) p += v3[t] * l4_b[t] + u256[t] * l1_b[t];
    if (t < 2)   p += u527[t] * sl_b[t];
    if (t < 8)   p += u527[2 + t] * st_b[t];
    p += u527[10 + t] * seg_b[t];
    p += __shfl_xor(p, 1);  p += __shfl_xor(p, 2);  p += __shfl_xor(p, 4);
    p += __shfl_xor(p, 8);  p += __shfl_xor(p, 16); p += __shfl_xor(p, 32);
    if ((t & 63) == 0) red[t >> 6] = p;
    __syncthreads();
    if (t == 0) {
        float s = l7_b[0];
        for (int i = 0; i < 8; ++i) s += red[i];
        *bias_out = s;
    }
}

__global__ void k_seg(const float* __restrict__ seg_w, const float* __restrict__ u527,
                      float* __restrict__ wsp) {
    int j = blockIdx.x * 256 + threadIdx.x;
    if (j >= 1276) return;
    float s = 0.f;
    for (int i = 0; i < 512; ++i) s += u527[10 + i] * seg_w[i*1276 + j];
    wsp[16 + j] = s;
}

// fp8 weights for MX 32x32x64 MFMA, W as the A-operand.
// Unit u = kc*2 + h (kc = K-chunk of 64): 32KB at u*32768. Wave region w*4096.
// Within: tile tau (q = 2h+tau) at tau*2048; part p (k 16B-half) at p*1024; lane*16 + b.
// A frag: gate-row = (lane&31), k = kc*64 + (lane>>5)*32 + p*16 + b.
// n = q*256 + 32w + (lane&31).
__global__ void k_wcq(const float* __restrict__ w_ih, const float* __restrict__ b_ih,
                      const float* __restrict__ w_hh, const float* __restrict__ b_hh,
                      uint8* __restrict__ wcq, float* __restrict__ biasg) {
    int idx = blockIdx.x * 256 + threadIdx.x;
    if (idx < 1024) biasg[idx] = b_ih[idx] + b_hh[idx];
    if (idx < 327680) {
        int u   = idx >> 15;
        int r   = idx & 32767;
        int w   = r >> 12;
        int r2  = r & 4095;
        int tau = r2 >> 11;
        int r3  = r2 & 2047;
        int p   = r3 >> 10;
        int r4  = r3 & 1023;
        int lane = r4 >> 4;
        int b   = r4 & 15;
        int kc  = u >> 1, h = u & 1;
        int q   = 2*h + tau;
        int n   = q*256 + 32*w + (lane & 31);
        int k   = kc*64 + ((lane >> 5) << 5) + p*16 + b;
        float v = 0.f;
        if (k < 56)       v = w_ih[n*56 + k];
        else if (k >= 64) v = w_hh[n*256 + (k - 64)];
        uint32 pk = __builtin_amdgcn_cvt_pk_fp8_f32(v, 0.f, 0, false);
        wcq[idx] = (uint8)(pk & 0xff);
    }
}

__global__ void k_spatial(const float* __restrict__ sp, const float* __restrict__ wsp,
                          const float* __restrict__ bias, float* __restrict__ out) {
    int row  = blockIdx.x * 4 + (threadIdx.x >> 6);
    int lane = threadIdx.x & 63;
    const float* rp = sp + (size_t)row * 1297;
    float s = 0.f;
    for (int k = lane; k < 1297; k += 64) s += rp[k] * wsp[k];
    s += __shfl_xor(s, 1);  s += __shfl_xor(s, 2);  s += __shfl_xor(s, 4);
    s += __shfl_xor(s, 8);  s += __shfl_xor(s, 16); s += __shfl_xor(s, 32);
    if (lane == 0) out[row] = s + bias[0];
}

// ---------------- LSTM v14: MX-scaled 32x32x64 fp8 MFMA (unit scales) ----------------
// 512 thr / 8 waves / 1 block/CU, 256 blocks x 64 rows. 10 fp8 units/step (kc,half)
// through a per-wave 3-slot ring, issue-after-consume depth-3, 1 barrier/step.
// Per phase per wave: 2 W A-tiles (32 gate-cols x 64K) x 2 activation B-tiles (64K x 32 rows)
// = 4 mfma_scale_f32_32x32x64_f8f6f4 with e8m0 scale 0x7F (=1.0). 40 MFMA/wave/step.
// Activations double-buffered, padded strides (Xa 80B/row, Ahs 272B/row), b128-aligned.
__launch_bounds__(512, 2)
__global__ void k_lstm(const float* __restrict__ temporal, const uint8* __restrict__ wcq,
                       const float* __restrict__ biasg, const float* __restrict__ ah,
                       float* __restrict__ out) {
    __shared__ __attribute__((aligned(16))) char  Ring[3 * 32768];   // 98304 B
    __shared__ __attribute__((aligned(16))) char  Ahs[2 * 64 * 272]; // 34816 B fp8 h
    __shared__ __attribute__((aligned(16))) char  Xa[2 * 64 * 80];   // 10240 B fp8 x
    __shared__ __attribute__((aligned(16))) float Xf[64 * 56];       // 14336 B f32 x stage
    __shared__ __attribute__((aligned(16))) char  Xd[2048];          //  2048 B dummy

    const int tid  = threadIdx.x;
    const int lane = tid & 63;
    const int w    = tid >> 6;          // 0..7
    const int l31  = lane & 31;
    const int lh   = lane >> 5;         // 0..1 (K-group)
    const int row0 = blockIdx.x * 64;

    // bias fragments: breg[q][reg], hd(reg) = 32w + (reg&3) + 8*(reg>>2) + 4*lh
    f32x16 breg[4];
#pragma unroll
    for (int q = 0; q < 4; ++q)
#pragma unroll
        for (int grp = 0; grp < 4; ++grp) {
            f32x4 bb = *reinterpret_cast<const f32x4*>(biasg + q*256 + 32*w + 8*grp + 4*lh);
#pragma unroll
            for (int j = 0; j < 4; ++j) breg[q][grp*4 + j] = bb[j];
        }
    f32x4 ahv4[4];
#pragma unroll
    for (int grp = 0; grp < 4; ++grp)
        ahv4[grp] = *reinterpret_cast<const f32x4*>(ah + 32*w + 8*grp + 4*lh);

    // x staging source offsets (bytes): wave w covers Xf bytes [2w*1024, 2w*1024+2048)
    long xo0, xo1;
    {
        int b0 = (2*w + 0)*1024 + lane*16;
        int b1 = (2*w + 1)*1024 + lane*16;
        xo0 = (long)(b0/224)*21504 + (b0 % 224);
        xo1 = (long)(b1/224)*21504 + (b1 % 224);
    }
    const char* xsrc = (const char*)(temporal + (size_t)row0 * 5376);

    auto stage_w = [&](int slot, int uu) {
        const uint8* src = wcq + uu*32768 + w*4096 + lane*16;
        char* dst = Ring + slot*32768 + w*4096 + lane*16;
#pragma unroll
        for (int i = 0; i < 4; ++i)
            __builtin_amdgcn_global_load_lds(
                (const __attribute__((address_space(1))) uint32*)(src + i*1024),
                (__attribute__((address_space(3))) uint32*)(dst + i*1024), 16, 0, 0);
    };
    auto stage_x = [&](int tt) {
        if (w < 7) {
            const char* s0 = xsrc + xo0 + (size_t)tt*224;
            const char* s1 = xsrc + xo1 + (size_t)tt*224;
            float* d0 = Xf + (2*w)*256 + lane*4;
            float* d1 = Xf + (2*w+1)*256 + lane*4;
            __builtin_amdgcn_global_load_lds((const __attribute__((address_space(1))) uint32*)s0,
                                             (__attribute__((address_space(3))) uint32*)d0, 16, 0, 0);
            __builtin_amdgcn_global_load_lds((const __attribute__((address_space(1))) uint32*)s1,
                                             (__attribute__((address_space(3))) uint32*)d1, 16, 0, 0);
        } else {   // keep vmcnt uniform across waves
            const char* s0 = xsrc + lane*16;
            __builtin_amdgcn_global_load_lds((const __attribute__((address_space(1))) uint32*)s0,
                                             (__attribute__((address_space(3))) uint32*)(Xd + lane*16), 16, 0, 0);
            __builtin_amdgcn_global_load_lds((const __attribute__((address_space(1))) uint32*)(s0 + 1024),
                                             (__attribute__((address_space(3))) uint32*)(Xd + 1024 + lane*16), 16, 0, 0);
        }
    };
    auto conv_x = [&](int buf) {        // Xf (f32) -> Xa[buf] fp8, row stride 80
        int xr = tid >> 3, xs = tid & 7;
        uint32 lo = 0u, hi = 0u;
        if (xs < 7) {
            const float* xf = Xf + xr*56 + xs*8;
            f32x4 a = *reinterpret_cast<const f32x4*>(xf);
            f32x4 b = *reinterpret_cast<const f32x4*>(xf + 4);
            lo = __builtin_amdgcn_cvt_pk_fp8_f32(a[0], a[1], 0, false);
            lo = __builtin_amdgcn_cvt_pk_fp8_f32(a[2], a[3], lo, true);
            hi = __builtin_amdgcn_cvt_pk_fp8_f32(b[0], b[1], 0, false);
            hi = __builtin_amdgcn_cvt_pk_fp8_f32(b[2], b[3], hi, true);
        }
        uint32* p = reinterpret_cast<uint32*>(Xa + buf*5120 + xr*80 + xs*8);
        p[0] = lo; p[1] = hi;
    };

    // ---- prologue: x0 + units 0,1,2; zero Ahs[0]; convert x0 -> Xa[0] ----
    stage_x(0);
    stage_w(0, 0); stage_w(1, 1); stage_w(2, 2);
    for (int i = tid; i < 4352; i += 512)
        reinterpret_cast<uint32*>(Ahs)[i] = 0u;
    asm volatile("s_waitcnt vmcnt(0)" ::: "memory");
    __builtin_amdgcn_s_barrier();
    conv_x(0);
    asm volatile("s_waitcnt lgkmcnt(0)" ::: "memory");
    __builtin_amdgcn_s_barrier();

    f32x16 cst[2], hv[2];               // [bt]: c state / h(t)
#pragma unroll
    for (int bt = 0; bt < 2; ++bt)
#pragma unroll
        for (int r = 0; r < 16; ++r) cst[bt][r] = 0.f;

    int sl = 0;                         // ring slot of current unit (continuous mod 3)
#pragma unroll 1
    for (int t = 0; t < 96; ++t) {
        const int par = t & 1, nxt = par ^ 1;
        f32x16 acc[4][2];               // [q][bt]
#pragma unroll
        for (int q = 0; q < 4; ++q)
#pragma unroll
            for (int bt = 0; bt < 2; ++bt)
                acc[q][bt] = breg[q];

#pragma unroll 1
        for (int c = 0; c < 10; ++c) {
            if (c >= 1 && c <= 3) asm volatile("s_waitcnt vmcnt(10)" ::: "memory");
            else                  asm volatile("s_waitcnt vmcnt(8)"  ::: "memory");

            const char* wb = Ring + sl*32768 + w*4096 + lane*16;
            i32x4 a0l = *reinterpret_cast<const i32x4*>(wb);
            i32x4 a0h = *reinterpret_cast<const i32x4*>(wb + 1024);
            i32x4 a1l = *reinterpret_cast<const i32x4*>(wb + 2048);
            i32x4 a1h = *reinterpret_cast<const i32x4*>(wb + 3072);
            i32x8 A0 = __builtin_shufflevector(a0l, a0h, 0,1,2,3,4,5,6,7);
            i32x8 A1 = __builtin_shufflevector(a1l, a1h, 0,1,2,3,4,5,6,7);

            const int kc = c >> 1, h = c & 1;
            i32x8 B[2];
#pragma unroll
            for (int bt = 0; bt < 2; ++bt) {
                int row = bt*32 + l31;
                const char* bp;
                if (kc == 0) bp = Xa  + par*5120  + row*80  + (lh << 5);
                else         bp = Ahs + par*17408 + row*272 + (kc - 1)*64 + (lh << 5);
                i32x4 blo = *reinterpret_cast<const i32x4*>(bp);
                i32x4 bhi = *reinterpret_cast<const i32x4*>(bp + 16);
                B[bt] = __builtin_shufflevector(blo, bhi, 0,1,2,3,4,5,6,7);
            }
#pragma unroll
            for (int bt = 0; bt < 2; ++bt) {
                acc[2*h+0][bt] = __builtin_amdgcn_mfma_scale_f32_32x32x64_f8f6f4(
                    A0, B[bt], acc[2*h+0][bt], 0, 0, 0, 0x7f7f7f7f, 0, 0x7f7f7f7f);
                acc[2*h+1][bt] = __builtin_amdgcn_mfma_scale_f32_32x32x64_f8f6f4(
                    A1, B[bt], acc[2*h+1][bt], 0, 0, 0, 0x7f7f7f7f, 0, 0x7f7f7f7f);
            }
            // issue-after-consume: unit c+3 reuses the slot just read
            {
                int u3 = c + 3; if (u3 >= 10) u3 -= 10;
                stage_w(sl, u3);
            }
            if (c == 0) stage_x(t < 95 ? t + 1 : 95);
            sl = sl + 1; if (sl >= 3) sl -= 3;
        }

        // ---- gates -> c, h (hw-rate transcendentals; thread-local quad) ----
#pragma unroll
        for (int bt = 0; bt < 2; ++bt)
#pragma unroll
            for (int r = 0; r < 16; ++r) {
                float ig = sigmoid_hw(acc[0][bt][r]);
                float fg = sigmoid_hw(acc[1][bt][r]);
                float gt = tanh_hw  (acc[2][bt][r]);
                float og = sigmoid_hw(acc[3][bt][r]);
                float cn = fg * cst[bt][r] + ig * gt;
                cst[bt][r] = cn;
                hv[bt][r] = og * tanh_hw(cn);
            }

        if (t < 95) {
            // h(t) -> Ahs[nxt]: 4 packed b32 per bt; x(t+1) -> Xa[nxt]
#pragma unroll
            for (int bt = 0; bt < 2; ++bt) {
                int row = bt*32 + l31;
                char* dst = Ahs + nxt*17408 + row*272 + 32*w + 4*lh;
#pragma unroll
                for (int grp = 0; grp < 4; ++grp) {
                    uint32 pk = __builtin_amdgcn_cvt_pk_fp8_f32(
                        hv[bt][grp*4+0], hv[bt][grp*4+1], 0, false);
                    pk = __builtin_amdgcn_cvt_pk_fp8_f32(
                        hv[bt][grp*4+2], hv[bt][grp*4+3], pk, true);
                    *reinterpret_cast<uint32*>(dst + grp*8) = pk;
                }
            }
            asm volatile("s_waitcnt vmcnt(12)" ::: "memory");   // x(t+1) landed in Xf
            conv_x(nxt);
            asm volatile("s_waitcnt lgkmcnt(0)" ::: "memory");
            __builtin_amdgcn_s_barrier();       // the ONE barrier: writes visible
        }
    }

    // ---- epilogue: out[row] += ah . h_T[row] ----
    {
        float part[2];
#pragma unroll
        for (int bt = 0; bt < 2; ++bt) {
            float s = 0.f;
#pragma unroll
            for (int grp = 0; grp < 4; ++grp)
#pragma unroll
                for (int j = 0; j < 4; ++j)
                    s += ahv4[grp][j] * hv[bt][grp*4 + j];
            s += __shfl_xor(s, 32);     // combine the two K-groups (lh halves)
            part[bt] = s;
        }
        __builtin_amdgcn_s_barrier();
        asm volatile("s_waitcnt vmcnt(0)" ::: "memory");   // drain tail prefetches
        float* sc = reinterpret_cast<float*>(Ring);
        if (lane < 32)
#pragma unroll
            for (int bt = 0; bt < 2; ++bt)
                sc[w*64 + bt*32 + l31] = part[bt];
        asm volatile("s_waitcnt lgkmcnt(0)" ::: "memory");
        __builtin_amdgcn_s_barrier();
        if (tid < 64) {
            float s = 0.f;
#pragma unroll
            for (int wv = 0; wv < 8; ++wv) s += sc[wv*64 + tid];
            out[row0 + tid] += s;
        }
    }
}

// ---------------- launch ----------------
extern "C" void kernel_launch(void* const* d_in, const int* in_sizes, int n_in,
                              void* d_out, int out_size, void* d_ws, size_t ws_size,
                              hipStream_t stream) {
    const float* spatial  = (const float*)d_in[0];
    const float* temporal = (const float*)d_in[1];
    const float* sl_w = (const float*)d_in[2];  const float* sl_b = (const float*)d_in[3];
    const float* st_w = (const float*)d_in[4];  const float* st_b = (const float*)d_in[5];
    const float* seg_w = (const float*)d_in[6]; const float* seg_b = (const float*)d_in[7];
    const float* l1_w = (const float*)d_in[8];  const float* l1_b = (const float*)d_in[9];
    const float* l2_w = (const float*)d_in[10]; const float* l2_b = (const float*)d_in[11];
    const float* w_ih = (const float*)d_in[12]; const float* b_ih = (const float*)d_in[13];
    const float* w_hh = (const float*)d_in[14]; const float* b_hh = (const float*)d_in[15];
    const float* l4_w = (const float*)d_in[16]; const float* l4_b = (const float*)d_in[17];
    const float* l5_w = (const float*)d_in[18]; const float* l5_b = (const float*)d_in[19];
    const float* l6_w = (const float*)d_in[20]; const float* l6_b = (const float*)d_in[21];
    const float* l7_w = (const float*)d_in[22]; const float* l7_b = (const float*)d_in[23];

    char* ws = (char*)d_ws;
    float*  wsp   = (float*)(ws + WS_WSP);
    float*  ah    = (float*)(ws + WS_AH);
    float*  u527  = (float*)(ws + WS_U527);
    float*  biasT = (float*)(ws + WS_BIAS);
    float*  biasg = (float*)(ws + WS_BIASG);
    uint8*  wcq   = (uint8*)(ws + WS_WC);

    float* out = (float*)d_out;

    hipLaunchKernelGGL(k_head, dim3(1), dim3(512), 0, stream,
                       sl_w, sl_b, st_w, st_b, seg_b, l1_w, l1_b, l2_w, l2_b,
                       l4_w, l4_b, l5_w, l5_b, l6_w, l6_b, l7_w, l7_b,
                       wsp, ah, u527, biasT);
    hipLaunchKernelGGL(k_seg, dim3(5), dim3(256), 0, stream, seg_w, u527, wsp);
    hipLaunchKernelGGL(k_wcq, dim3(1280), dim3(256), 0, stream,
                       w_ih, b_ih, w_hh, b_hh, wcq, biasg);
    hipLaunchKernelGGL(k_spatial, dim3(16384/4), dim3(256), 0, stream,
                       spatial, wsp, biasT, out);
    hipLaunchKernelGGL(k_lstm, dim3(256), dim3(512), 0, stream,
                       temporal, wcq, biasg, ah, out);
}

// Round 16
// 1158.381 us; speedup vs baseline: 9.1665x; 9.1665x over previous
//
#include <hip/hip_runtime.h>
#include <hip/hip_bf16.h>
#include <math.h>

typedef __bf16 bf16_t;
typedef float  f32x4  __attribute__((ext_vector_type(4)));
typedef unsigned int uint32;
typedef unsigned char uint8;
typedef long long ll_t;
typedef long long ll2 __attribute__((ext_vector_type(2)));

// ---------------- workspace layout (bytes) ----------------
#define WS_WSP    0        // 1297 f32
#define WS_AH     5248     // 256 f32
#define WS_U527   6272     // 527 f32
#define WS_BIAS   8384     // 1 f32
#define WS_BIASG  8448     // 1024 f32
#define WS_WC     12544    // 327680 B fp8 weights: 10 units x 32KB

// Hardware-rate gate math: v_exp_f32 (exp2) + v_rcp_f32, ~1ulp, exact saturation.
__device__ __forceinline__ float sigmoid_hw(float x) {
    float e = __builtin_amdgcn_exp2f(-1.44269504f * x);
    return __builtin_amdgcn_rcpf(1.f + e);
}
__device__ __forceinline__ float tanh_hw(float x) {
    float e = __builtin_amdgcn_exp2f(2.88539008f * x);
    return 1.f - 2.f * __builtin_amdgcn_rcpf(1.f + e);
}

// ---------------- head/spatial weight composition (tiny) ----------------
__global__ void k_head(const float* __restrict__ sl_w, const float* __restrict__ sl_b,
                       const float* __restrict__ st_w, const float* __restrict__ st_b,
                       const float* __restrict__ seg_b,
                       const float* __restrict__ l1_w, const float* __restrict__ l1_b,
                       const float* __restrict__ l2_w, const float* __restrict__ l2_b,
                       const float* __restrict__ l4_w, const float* __restrict__ l4_b,
                       const float* __restrict__ l5_w, const float* __restrict__ l5_b,
                       const float* __restrict__ l6_w, const float* __restrict__ l6_b,
                       const float* __restrict__ l7_w, const float* __restrict__ l7_b,
                       float* __restrict__ wsp, float* __restrict__ ah,
                       float* __restrict__ u527_out, float* __restrict__ bias_out) {
    __shared__ float v2[128], v3[256], aa[384], u256[256], u527[527];
    __shared__ float red[8];
    const int t = threadIdx.x;   // 512 threads

    if (t < 128) { float s = 0.f; for (int i = 0; i < 128; ++i) s += l7_w[i] * l6_w[i*128 + t]; v2[t] = s; }
    __syncthreads();
    if (t < 256) { float s = 0.f; for (int i = 0; i < 128; ++i) s += v2[i] * l5_w[i*256 + t]; v3[t] = s; }
    __syncthreads();
    if (t < 384) { float s = 0.f; for (int i = 0; i < 256; ++i) s += v3[i] * l4_w[i*384 + t]; aa[t] = s; }
    __syncthreads();
    if (t < 256) { float s = 0.f; for (int i = 0; i < 128; ++i) s += aa[i] * l2_w[i*256 + t]; u256[t] = s; }
    if (t < 256) ah[t] = aa[128 + t];
    __syncthreads();
    for (int j = t; j < 527; j += 512) {
        float s = 0.f;
        for (int i = 0; i < 256; ++i) s += u256[i] * l1_w[i*527 + j];
        u527[j] = s; u527_out[j] = s;
    }
    __syncthreads();
    if (t < 4)              { float s = 0.f; for (int i = 0; i < 2; ++i) s += u527[i]     * sl_w[i*4  + t];      wsp[t] = s; }
    else if (t < 16)        { int c = t - 4;  float s = 0.f; for (int i = 0; i < 8; ++i) s += u527[2+i] * st_w[i*12 + c]; wsp[t] = s; }
    else if (t < 21)        { wsp[1292 + (t - 16)] = u527[522 + (t - 16)]; }
    float p = 0.f;
    if (t < 128) p += l7_w[t] * l6_b[t] + v2[t] * l5_b[t] + aa[t] * l2_b[t];
    if (t < 256) p += v3[t] * l4_b[t] + u256[t] * l1_b[t];
    if (t < 2)   p += u527[t] * sl_b[t];
    if (t < 8)   p += u527[2 + t] * st_b[t];
    p += u527[10 + t] * seg_b[t];
    p += __shfl_xor(p, 1);  p += __shfl_xor(p, 2);  p += __shfl_xor(p, 4);
    p += __shfl_xor(p, 8);  p += __shfl_xor(p, 16); p += __shfl_xor(p, 32);
    if ((t & 63) == 0) red[t >> 6] = p;
    __syncthreads();
    if (t == 0) {
        float s = l7_b[0];
        for (int i = 0; i < 8; ++i) s += red[i];
        *bias_out = s;
    }
}

__global__ void k_seg(const float* __restrict__ seg_w, const float* __restrict__ u527,
                      float* __restrict__ wsp) {
    int j = blockIdx.x * 256 + threadIdx.x;
    if (j >= 1276) return;
    float s = 0.f;
    for (int i = 0; i < 512; ++i) s += u527[10 + i] * seg_w[i*1276 + j];
    wsp[16 + j] = s;
}

// fp8 weights, W as the MFMA A-operand, PAIR-PACKED for ds_read_b128.
// Unit kk = 32KB at kk*32768; wave region w*4096; issue j (0..3) at j*1024;
// lane block lane*16 (16 B): bytes 0..7 = frag f=2j, bytes 8..15 = frag f=2j+1.
// Frag f = ht*4+q: n = q*256 + 32w + 16ht + (lane&15); k = kk*32 + (lane>>4)*8 + e.
__global__ void k_wcq(const float* __restrict__ w_ih, const float* __restrict__ b_ih,
                      const float* __restrict__ w_hh, const float* __restrict__ b_hh,
                      uint8* __restrict__ wcq, float* __restrict__ biasg) {
    int idx = blockIdx.x * 256 + threadIdx.x;
    if (idx < 1024) biasg[idx] = b_ih[idx] + b_hh[idx];
    if (idx < 327680) {
        int kk = idx >> 15;
        int r  = idx & 32767;
        int w  = r >> 12;
        int r2 = r & 4095;
        int j  = r2 >> 10;
        int r3 = r2 & 1023;
        int lane = r3 >> 4;
        int b  = r3 & 15;
        int f  = 2*j + (b >> 3);
        int e  = b & 7;
        int ht = f >> 2, q = f & 3;
        int n = q*256 + 32*w + 16*ht + (lane & 15);
        int k = kk*32 + ((lane >> 4) << 3) + e;
        float v = 0.f;
        if (k < 56)       v = w_ih[n*56 + k];
        else if (k >= 64) v = w_hh[n*256 + (k - 64)];
        uint32 pk = __builtin_amdgcn_cvt_pk_fp8_f32(v, 0.f, 0, false);
        wcq[idx] = (uint8)(pk & 0xff);
    }
}

__global__ void k_spatial(const float* __restrict__ sp, const float* __restrict__ wsp,
                          const float* __restrict__ bias, float* __restrict__ out) {
    int row  = blockIdx.x * 4 + (threadIdx.x >> 6);
    int lane = threadIdx.x & 63;
    const float* rp = sp + (size_t)row * 1297;
    float s = 0.f;
    for (int k = lane; k < 1297; k += 64) s += rp[k] * wsp[k];
    s += __shfl_xor(s, 1);  s += __shfl_xor(s, 2);  s += __shfl_xor(s, 4);
    s += __shfl_xor(s, 8);  s += __shfl_xor(s, 16); s += __shfl_xor(s, 32);
    if (lane == 0) out[row] = s + bias[0];
}

// ---------------- LSTM v13 (final): double-buffered activations, 1 barrier/step --------
// 512 thr / 8 waves / 1 block/CU, 256 blocks x 64 rows. 10 fp8 units/step through a
// per-wave 3-slot ring with issue-after-consume depth-3 prefetch (96KB in flight across
// the gate window). Activations double-buffered (Xa[2], Ah[2], granule-XOR swizzle) ->
// exactly ONE lgkmcnt+barrier per step. Gates via v_exp_f32/v_rcp_f32.
__launch_bounds__(512, 2)
__global__ void k_lstm(const float* __restrict__ temporal, const uint8* __restrict__ wcq,
                       const float* __restrict__ biasg, const float* __restrict__ ah,
                       float* __restrict__ out) {
    __shared__ __attribute__((aligned(16))) char  Ring[3 * 32768];   // 98304 B
    __shared__ __attribute__((aligned(16))) char  Ah[2 * 16384];     // 32768 B fp8 h
    __shared__ __attribute__((aligned(16))) char  Xa[2 * 4096];      //  8192 B fp8 x
    __shared__ __attribute__((aligned(16))) float Xf[64 * 56];       // 14336 B f32 x stage
    __shared__ __attribute__((aligned(16))) char  Xd[2048];          //  2048 B dummy

    const int tid  = threadIdx.x;
    const int lane = tid & 63;
    const int w    = tid >> 6;          // 0..7
    const int l15  = lane & 15;
    const int l4q  = lane >> 4;         // 0..3
    const int row0 = blockIdx.x * 64;

    f32x4 bias[2][4];                   // [ht][q]
#pragma unroll
    for (int ht = 0; ht < 2; ++ht)
#pragma unroll
        for (int q = 0; q < 4; ++q)
            bias[ht][q] = *reinterpret_cast<const f32x4*>(biasg + q*256 + 32*w + 16*ht + 4*l4q);
    f32x4 ahv[2];
#pragma unroll
    for (int ht = 0; ht < 2; ++ht)
        ahv[ht] = *reinterpret_cast<const f32x4*>(ah + 32*w + 16*ht + 4*l4q);

    // per-rt B-read invariants (row = rt*16 + l15)
    int hbase[4], hswz[4], xbase_o[4];
#pragma unroll
    for (int rt = 0; rt < 4; ++rt) {
        int row = rt*16 + l15;
        hswz[rt]   = row & 7;
        hbase[rt]  = row*256 + (l4q << 3);
        xbase_o[rt]= row*64;
    }

    // x staging source offsets (bytes): wave w covers Xf bytes [2w*1024, 2w*1024+2048)
    long xo0, xo1;
    {
        int b0 = (2*w + 0)*1024 + lane*16;
        int b1 = (2*w + 1)*1024 + lane*16;
        xo0 = (long)(b0/224)*21504 + (b0 % 224);
        xo1 = (long)(b1/224)*21504 + (b1 % 224);
    }
    const char* xsrc = (const char*)(temporal + (size_t)row0 * 5376);

    auto stage_w = [&](int slot, int uu) {
        const uint8* src = wcq + uu*32768 + w*4096 + lane*16;
        char* dst = Ring + slot*32768 + w*4096 + lane*16;
#pragma unroll
        for (int i = 0; i < 4; ++i)
            __builtin_amdgcn_global_load_lds(
                (const __attribute__((address_space(1))) uint32*)(src + i*1024),
                (__attribute__((address_space(3))) uint32*)(dst + i*1024), 16, 0, 0);
    };
    auto stage_x = [&](int tt) {
        if (w < 7) {
            const char* s0 = xsrc + xo0 + (size_t)tt*224;
            const char* s1 = xsrc + xo1 + (size_t)tt*224;
            float* d0 = Xf + (2*w)*256 + lane*4;
            float* d1 = Xf + (2*w+1)*256 + lane*4;
            __builtin_amdgcn_global_load_lds((const __attribute__((address_space(1))) uint32*)s0,
                                             (__attribute__((address_space(3))) uint32*)d0, 16, 0, 0);
            __builtin_amdgcn_global_load_lds((const __attribute__((address_space(1))) uint32*)s1,
                                             (__attribute__((address_space(3))) uint32*)d1, 16, 0, 0);
        } else {   // keep vmcnt uniform across waves
            const char* s0 = xsrc + lane*16;
            __builtin_amdgcn_global_load_lds((const __attribute__((address_space(1))) uint32*)s0,
                                             (__attribute__((address_space(3))) uint32*)(Xd + lane*16), 16, 0, 0);
            __builtin_amdgcn_global_load_lds((const __attribute__((address_space(1))) uint32*)(s0 + 1024),
                                             (__attribute__((address_space(3))) uint32*)(Xd + 1024 + lane*16), 16, 0, 0);
        }
    };
    auto conv_x = [&](int buf) {        // Xf (f32) -> Xa[buf] fp8, swizzled granules
        int xr = tid >> 3, xs = tid & 7;   // row, granule
        uint32 lo = 0u, hi = 0u;
        if (xs < 7) {
            const float* xf = Xf + xr*56 + xs*8;
            f32x4 a = *reinterpret_cast<const f32x4*>(xf);
            f32x4 b = *reinterpret_cast<const f32x4*>(xf + 4);
            lo = __builtin_amdgcn_cvt_pk_fp8_f32(a[0], a[1], 0, false);
            lo = __builtin_amdgcn_cvt_pk_fp8_f32(a[2], a[3], lo, true);
            hi = __builtin_amdgcn_cvt_pk_fp8_f32(b[0], b[1], 0, false);
            hi = __builtin_amdgcn_cvt_pk_fp8_f32(b[2], b[3], hi, true);
        }
        uint32* p = reinterpret_cast<uint32*>(Xa + buf*4096 + xr*64 + ((xs ^ (xr & 7)) << 3));
        p[0] = lo; p[1] = hi;
    };

    // ---- prologue: x0 + units 0,1,2; zero Ah[0]; convert x0 -> Xa[0] ----
    stage_x(0);
    stage_w(0, 0); stage_w(1, 1); stage_w(2, 2);
    for (int i = tid; i < 4096; i += 512)
        reinterpret_cast<uint32*>(Ah)[i] = 0u;
    asm volatile("s_waitcnt vmcnt(0)" ::: "memory");
    __builtin_amdgcn_s_barrier();
    conv_x(0);
    asm volatile("s_waitcnt lgkmcnt(0)" ::: "memory");
    __builtin_amdgcn_s_barrier();

    f32x4 cst[4][2];                    // c state [rt][ht]
    f32x4 hv[4][2];                     // h(t), carried to epilogue
#pragma unroll
    for (int rt = 0; rt < 4; ++rt)
#pragma unroll
        for (int ht = 0; ht < 2; ++ht) cst[rt][ht] = (f32x4){0.f,0.f,0.f,0.f};

    int sl = 0;                         // ring slot of current unit (continuous mod 3)
#pragma unroll 1
    for (int t = 0; t < 96; ++t) {
        const int par = t & 1, nxt = par ^ 1;
        f32x4 acc[4][2][4];             // [rt][ht][q]
#pragma unroll
        for (int rt = 0; rt < 4; ++rt)
#pragma unroll
            for (int ht = 0; ht < 2; ++ht)
#pragma unroll
                for (int q = 0; q < 4; ++q)
                    acc[rt][ht][q] = bias[ht][q];

#pragma unroll 1
        for (int c = 0; c < 10; ++c) {
            // counted wait for unit c: phases 1-3 carry the 2 x-loads in the queue
            if (c >= 1 && c <= 3) asm volatile("s_waitcnt vmcnt(10)" ::: "memory");
            else                  asm volatile("s_waitcnt vmcnt(8)"  ::: "memory");

            const char* wb = Ring + sl*32768 + w*4096 + lane*16;
            ll_t Af[8];
#pragma unroll
            for (int j = 0; j < 4; ++j) {
                ll2 pr = *reinterpret_cast<const ll2*>(wb + j*1024);
                Af[2*j]   = pr.x;
                Af[2*j+1] = pr.y;
            }
            ll_t Bv[4];
            if (c < 2) {
#pragma unroll
                for (int rt = 0; rt < 4; ++rt)
                    Bv[rt] = *reinterpret_cast<const ll_t*>(
                        Xa + par*4096 + xbase_o[rt] + (((c*4 + l4q) ^ hswz[rt]) << 3));
            } else {
#pragma unroll
                for (int rt = 0; rt < 4; ++rt)
                    Bv[rt] = *reinterpret_cast<const ll_t*>(
                        Ah + par*16384 + hbase[rt] + (((c-2) ^ hswz[rt]) << 5));
            }
#pragma unroll
            for (int ht = 0; ht < 2; ++ht)
#pragma unroll
                for (int q = 0; q < 4; ++q) {
                    ll_t A = Af[ht*4 + q];
#pragma unroll
                    for (int rt = 0; rt < 4; ++rt)
                        acc[rt][ht][q] = __builtin_amdgcn_mfma_f32_16x16x32_fp8_fp8(
                            A, Bv[rt], acc[rt][ht][q], 0, 0, 0);
                }
            // issue-after-consume: unit c+3 reuses the slot just read
            {
                int u3 = c + 3; if (u3 >= 10) u3 -= 10;
                stage_w(sl, u3);
            }
            if (c == 0) stage_x(t < 95 ? t + 1 : 95);
            sl = sl + 1; if (sl >= 3) sl -= 3;
        }

        // ---- gates -> c, h (hw-rate transcendentals; thread-local) ----
#pragma unroll
        for (int rt = 0; rt < 4; ++rt)
#pragma unroll
            for (int ht = 0; ht < 2; ++ht)
#pragma unroll
                for (int e = 0; e < 4; ++e) {
                    float ig = sigmoid_hw(acc[rt][ht][0][e]);
                    float fg = sigmoid_hw(acc[rt][ht][1][e]);
                    float gt = tanh_hw  (acc[rt][ht][2][e]);
                    float og = sigmoid_hw(acc[rt][ht][3][e]);
                    float cn = fg * cst[rt][ht][e] + ig * gt;
                    cst[rt][ht][e] = cn;
                    hv[rt][ht][e] = og * tanh_hw(cn);
                }

        if (t < 95) {
            // h(t) -> Ah[nxt] (swizzled b32 stores); x(t+1) -> Xa[nxt]
#pragma unroll
            for (int rt = 0; rt < 4; ++rt)
#pragma unroll
                for (int ht = 0; ht < 2; ++ht) {
                    uint32 pk = __builtin_amdgcn_cvt_pk_fp8_f32(hv[rt][ht][0], hv[rt][ht][1], 0, false);
                    pk = __builtin_amdgcn_cvt_pk_fp8_f32(hv[rt][ht][2], hv[rt][ht][3], pk, true);
                    int row = rt*16 + l15;
                    int g   = 4*w + 2*ht + (l4q >> 1);
                    *reinterpret_cast<uint32*>(
                        Ah + nxt*16384 + row*256 + ((g ^ ((row & 7) << 2)) << 3) + 4*(l4q & 1)) = pk;
                }
            asm volatile("s_waitcnt vmcnt(12)" ::: "memory");   // x(t+1) landed in Xf
            conv_x(nxt);
            asm volatile("s_waitcnt lgkmcnt(0)" ::: "memory");
            __builtin_amdgcn_s_barrier();       // the ONE barrier: writes visible
        }
    }

    // ---- epilogue: out[row] += ah . h_T[row] ----
    {
        float part[4];
#pragma unroll
        for (int rt = 0; rt < 4; ++rt) {
            float s = 0.f;
#pragma unroll
            for (int ht = 0; ht < 2; ++ht)
#pragma unroll
                for (int e = 0; e < 4; ++e)
                    s += ahv[ht][e] * hv[rt][ht][e];
            s += __shfl_xor(s, 16);
            s += __shfl_xor(s, 32);
            part[rt] = s;
        }
        __builtin_amdgcn_s_barrier();
        asm volatile("s_waitcnt vmcnt(0)" ::: "memory");   // drain tail prefetches before Ring reuse
        float* sc = reinterpret_cast<float*>(Ring);
        if (l4q == 0)
#pragma unroll
            for (int rt = 0; rt < 4; ++rt)
                sc[w*64 + rt*16 + l15] = part[rt];
        asm volatile("s_waitcnt lgkmcnt(0)" ::: "memory");
        __builtin_amdgcn_s_barrier();
        if (tid < 64) {
            float s = 0.f;
#pragma unroll
            for (int wv = 0; wv < 8; ++wv) s += sc[wv*64 + tid];
            out[row0 + tid] += s;
        }
    }
}

// ---------------- launch ----------------
extern "C" void kernel_launch(void* const* d_in, const int* in_sizes, int n_in,
                              void* d_out, int out_size, void* d_ws, size_t ws_size,
                              hipStream_t stream) {
    const float* spatial  = (const float*)d_in[0];
    const float* temporal = (const float*)d_in[1];
    const float* sl_w = (const float*)d_in[2];  const float* sl_b = (const float*)d_in[3];
    const float* st_w = (const float*)d_in[4];  const float* st_b = (const float*)d_in[5];
    const float* seg_w = (const float*)d_in[6]; const float* seg_b = (const float*)d_in[7];
    const float* l1_w = (const float*)d_in[8];  const float* l1_b = (const float*)d_in[9];
    const float* l2_w = (const float*)d_in[10]; const float* l2_b = (const float*)d_in[11];
    const float* w_ih = (const float*)d_in[12]; const float* b_ih = (const float*)d_in[13];
    const float* w_hh = (const float*)d_in[14]; const float* b_hh = (const float*)d_in[15];
    const float* l4_w = (const float*)d_in[16]; const float* l4_b = (const float*)d_in[17];
    const float* l5_w = (const float*)d_in[18]; const float* l5_b = (const float*)d_in[19];
    const float* l6_w = (const float*)d_in[20]; const float* l6_b = (const float*)d_in[21];
    const float* l7_w = (const float*)d_in[22]; const float* l7_b = (const float*)d_in[23];

    char* ws = (char*)d_ws;
    float*  wsp   = (float*)(ws + WS_WSP);
    float*  ah    = (float*)(ws + WS_AH);
    float*  u527  = (float*)(ws + WS_U527);
    float*  biasT = (float*)(ws + WS_BIAS);
    float*  biasg = (float*)(ws + WS_BIASG);
    uint8*  wcq   = (uint8*)(ws + WS_WC);

    float* out = (float*)d_out;

    hipLaunchKernelGGL(k_head, dim3(1), dim3(512), 0, stream,
                       sl_w, sl_b, st_w, st_b, seg_b, l1_w, l1_b, l2_w, l2_b,
                       l4_w, l4_b, l5_w, l5_b, l6_w, l6_b, l7_w, l7_b,
                       wsp, ah, u527, biasT);
    hipLaunchKernelGGL(k_seg, dim3(5), dim3(256), 0, stream, seg_w, u527, wsp);
    hipLaunchKernelGGL(k_wcq, dim3(1280), dim3(256), 0, stream,
                       w_ih, b_ih, w_hh, b_hh, wcq, biasg);
    hipLaunchKernelGGL(k_spatial, dim3(16384/4), dim3(256), 0, stream,
                       spatial, wsp, biasT, out);
    hipLaunchKernelGGL(k_lstm, dim3(256), dim3(512), 0, stream,
                       temporal, wcq, biasg, ah, out);
}